// Round 3
// baseline (91936.310 us; speedup 1.0000x reference)
//
#include <hip/hip_runtime.h>
#include <math.h>

#define BATCHN 4096
#define DIMN 128
#define HIDN 100
#define NSTEPSN 50
#define KPAD 8192   // strict-lower 8128 padded to 8192
#define HPN 101     // 100 hidden + 1 bias row
#define HP4 104     // HPN padded to multiple of 4 (pad weights = 0)
#define H3STR 112   // LDS h3 row stride (mult of 4 for b128 alignment)

struct Weights {
  const float *W1d,*b1d,*W2d,*b2d,*W3d,*b3d,*Wod,*bod;
  const float *W1f,*b1f,*W2f,*b2f,*W3f,*b3f;
  const float *Wdiag,*bdiag;
};

// ---- k -> (row) for strict-lower packed index: k = r*(r-1)/2 + c, c<r
__device__ inline int tri_row(int k) {
  float rf = (1.0f + sqrtf(1.0f + 8.0f*(float)k)) * 0.5f;
  int r = (int)rf;
  if (k < (r*(r-1))/2) --r;
  else if (k >= (r*(r+1))/2) ++r;
  return r;
}
// fill_triangular: cat = [v[:,128:], v[:,::-1]]; element (r,c) of the 128x128
// reshape comes from v[kk+128] if kk<8128 else v[16383-kk], kk = r*128+c.
__device__ inline int cat_vidx(int r, int c) {
  int kk = r*128 + c;
  return (kk < 8128) ? (kk + 128) : (16383 - kk);
}

// ---- init: k-major transposed strict-lower output weights, bias as h=100.
// WT[k][h], rows padded to HP4 with zeros; rows k>=8128 all zero.
__global__ __launch_bounds__(128) void init_wt(const float* __restrict__ Wo,
    const float* __restrict__ bo, float* __restrict__ WT)
{
  const int k = blockIdx.x;
  const int h = threadIdx.x;
  if (h >= HP4) return;
  float val = 0.f;
  if (k < 8128 && h < HPN) {
    int r = tri_row(k);
    int c = k - (r*(r-1))/2;
    int vidx = cat_vidx(r, c);
    val = (h < HIDN) ? Wo[h*8256 + vidx] : bo[vidx];
  }
  WT[(size_t)k*HP4 + h] = val;
}

// ---- init: diagonal weight slice, diag bias, h3 bias row
__global__ __launch_bounds__(256) void init_misc(const float* __restrict__ Wo,
    const float* __restrict__ bo, float* __restrict__ Wdiag,
    float* __restrict__ bdiag, float* __restrict__ h3t)
{
  int idx = blockIdx.x*256 + threadIdx.x;
  if (idx < HIDN*128) {
    int h = idx >> 7, r = idx & 127;
    Wdiag[idx] = Wo[h*8256 + cat_vidx(r, r)];
  } else if (idx < HIDN*128 + 128) {
    int r = idx - HIDN*128;
    bdiag[r] = bo[cat_vidx(r, r)];
  } else if (idx < HIDN*128 + 128 + BATCHN) {
    h3t[(size_t)HIDN*BATCHN + (idx - HIDN*128 - 128)] = 1.0f; // bias row of h3aug
  }
}

// ---- init: zero-padded Kx128 packs of the six narrow (.,100) matrices
__global__ __launch_bounds__(256) void init_pack(Weights wt, float* __restrict__ Wpack)
{
  int idx = blockIdx.x*256 + threadIdx.x;
  if (idx >= 6*128*128) return;
  int m = idx >> 14, rem = idx & 16383, c = rem >> 7, j = rem & 127;
  const float* src; int K;
  switch (m) {
    case 0: src = wt.W1d; K = 128; break;
    case 1: src = wt.W2d; K = 100; break;
    case 2: src = wt.W3d; K = 100; break;
    case 3: src = wt.W1f; K = 128; break;
    case 4: src = wt.W2f; K = 100; break;
    default: src = wt.W3f; K = 100; break;
  }
  Wpack[idx] = (j < HIDN && c < K) ? src[c*HIDN + j] : 0.f;
}

// ---- K1: both MLPs, drift out, vdiag, base, huber(t-1), entropy (unchanged)
__global__ __launch_bounds__(256) void mlp_kernel(
    const float* __restrict__ xin, const float* __restrict__ yhat_prev,
    const float* __restrict__ z_t, Weights wt, const float* __restrict__ Wpack,
    float* __restrict__ base, float* __restrict__ h3t,
    float* __restrict__ hub_sum, float* __restrict__ ent_sum, int t)
{
  __shared__ float Wl[128*128];
  __shared__ float xinl[16*132];
  __shared__ float hA[16*132];
  __shared__ float hB[16*132];
  __shared__ float redw[4];
  __shared__ float redh[16];

  const int tid = threadIdx.x;
  const int b0 = blockIdx.x * 16;
  const int bb = tid >> 4;
  const int jt = tid & 15;
  const int j0 = jt * 8;

  // stage x tile (16x128) + fused Huber(t-1)
  {
    const int f = tid * 8;
    const int lb = f >> 7, c = f & 127;
    const float* xp = xin + (size_t)(b0+lb)*DIMN + c;
    float4 x0 = *(const float4*)xp;
    float4 x1 = *(const float4*)(xp+4);
    *(float4*)&xinl[lb*132+c]   = x0;
    *(float4*)&xinl[lb*132+c+4] = x1;
    if (yhat_prev) {
      const float* yp = yhat_prev + (size_t)(b0+lb)*DIMN + c;
      float4 y0 = *(const float4*)yp;
      float4 y1 = *(const float4*)(yp+4);
      float xv[8] = {x0.x,x0.y,x0.z,x0.w,x1.x,x1.y,x1.z,x1.w};
      float yv[8] = {y0.x,y0.y,y0.z,y0.w,y1.x,y1.y,y1.z,y1.w};
      float hub = 0.f;
      #pragma unroll
      for (int i=0;i<8;++i) {
        float e = xv[i]-yv[i], ae = fabsf(e);
        hub += (ae <= 0.5f) ? 0.5f*e*e : fmaf(0.5f, ae, -0.125f);
      }
      #pragma unroll
      for (int off=32; off>0; off>>=1) hub += __shfl_down(hub, off);
      if ((tid & 63) == 0) redw[tid>>6] = hub;
    }
  }
  __syncthreads();
  if (yhat_prev && tid == 0)
    atomicAdd(&hub_sum[t-1], redw[0]+redw[1]+redw[2]+redw[3]);

  float acc[8];

  auto stage = [&](const float* __restrict__ Wg, int K) {
    __syncthreads();
    for (int i = tid*4; i < K*128; i += 1024)
      *(float4*)&Wl[i] = *(const float4*)&Wg[i];
    __syncthreads();
  };
  auto compute = [&](const float* inl, int K) {
    #pragma unroll
    for (int i=0;i<8;++i) acc[i] = 0.f;
    const float* inrow = inl + bb*132;
    #pragma unroll 4
    for (int c = 0; c < K; ++c) {
      const float xv = inrow[c];
      const float4 w0 = *(const float4*)&Wl[c*128 + j0];
      const float4 w1 = *(const float4*)&Wl[c*128 + j0 + 4];
      acc[0] = fmaf(xv, w0.x, acc[0]);
      acc[1] = fmaf(xv, w0.y, acc[1]);
      acc[2] = fmaf(xv, w0.z, acc[2]);
      acc[3] = fmaf(xv, w0.w, acc[3]);
      acc[4] = fmaf(xv, w1.x, acc[4]);
      acc[5] = fmaf(xv, w1.y, acc[5]);
      acc[6] = fmaf(xv, w1.z, acc[6]);
      acc[7] = fmaf(xv, w1.w, acc[7]);
    }
  };

  const float* P_W1d = Wpack;
  const float* P_W2d = Wpack + 16384;
  const float* P_W3d = Wpack + 32768;
  const float* P_W1f = Wpack + 49152;
  const float* P_W2f = Wpack + 65536;
  const float* P_W3f = Wpack + 81920;

  float h1reg[8], driftreg[8];

  // ---------- drift net ----------
  stage(P_W1d, 128); compute(xinl, 128);
  #pragma unroll
  for (int i=0;i<8;++i) {
    int j = j0+i;
    float v = (j < HIDN) ? tanhf(acc[i] + wt.b1d[j]) : 0.f;
    h1reg[i] = v; hA[bb*132+j] = v;
  }
  stage(P_W2d, 100); compute(hA, 100);
  #pragma unroll
  for (int i=0;i<8;++i) {
    int j = j0+i;
    float v = (j < HIDN) ? (tanhf(acc[i] + wt.b2d[j]) + h1reg[i]) : 0.f;
    hB[bb*132+j] = v;
  }
  stage(P_W3d, 100); compute(hB, 100);
  #pragma unroll
  for (int i=0;i<8;++i) {
    int j = j0+i;
    float v = (j < HIDN) ? fmaxf(acc[i] + wt.b3d[j], 0.f) : 0.f;
    hA[bb*132+j] = v;
  }
  stage(wt.Wod, 100); compute(hA, 100);
  #pragma unroll
  for (int i=0;i<8;++i) driftreg[i] = acc[i] + wt.bod[j0+i];

  // ---------- diff net ----------
  stage(P_W1f, 128); compute(xinl, 128);
  #pragma unroll
  for (int i=0;i<8;++i) {
    int j = j0+i;
    float v = (j < HIDN) ? tanhf(acc[i] + wt.b1f[j]) : 0.f;
    h1reg[i] = v; hB[bb*132+j] = v;
  }
  stage(P_W2f, 100); compute(hB, 100);
  #pragma unroll
  for (int i=0;i<8;++i) {
    int j = j0+i;
    float v = (j < HIDN) ? (tanhf(acc[i] + wt.b2f[j]) + h1reg[i]) : 0.f;
    hA[bb*132+j] = v;
  }
  stage(P_W3f, 100); compute(hA, 100);
  #pragma unroll
  for (int i=0;i<8;++i) {
    int j = j0+i;
    float v = (j < HIDN) ? fmaxf(acc[i] + wt.b3f[j], 0.f) : 0.f;
    hB[bb*132+j] = v;
    if (j < HIDN) h3t[(size_t)j*BATCHN + b0 + bb] = v;  // transposed for K2
  }
  stage(wt.Wdiag, 100); compute(hB, 100);

  // ---------- epilogue: vdiag, entropy, base ----------
  {
    float entacc = 0.f;
    const float* zp = z_t + (size_t)(b0+bb)*DIMN + j0;
    const float* xrow = xinl + bb*132 + j0;
    float o8[8];
    #pragma unroll
    for (int i=0;i<8;++i) {
      int j = j0+i;
      float vd = acc[i] + wt.bdiag[j];
      entacc += vd;                       // log(det) = sum of raw diag (log∘exp)
      o8[i] = xrow[i] + driftreg[i] + expf(vd) * zp[i];
    }
    float* bp = base + (size_t)(b0+bb)*DIMN + j0;
    *(float4*)bp     = make_float4(o8[0],o8[1],o8[2],o8[3]);
    *(float4*)(bp+4) = make_float4(o8[4],o8[5],o8[6],o8[7]);
    #pragma unroll
    for (int off=8; off>0; off>>=1) entacc += __shfl_down(entacc, off, 16);
    if (jt == 0) redh[bb] = entacc;
    __syncthreads();
    if (tid == 0) {
      float s = 0.f;
      #pragma unroll
      for (int i=0;i<16;++i) s += redh[i];
      atomicAdd(&ent_sum[t], s);
    }
  }
}

// ---- K2: heavy fused V=h3aug@W consumed into E=L_offdiag@z (V never stored)
// WT is k-major: per lane 8 consecutive k-rows -> sequential imm-offset streams.
// 512 threads = 8 waves x 2 batches; 16 batches/block; 256 blocks (1/CU).
__global__ __launch_bounds__(512) void heavy_kernel(
    const float* __restrict__ h3t,    // [101][4096]
    const float* __restrict__ WT,     // [8192][HP4] k-major
    const float* __restrict__ z_t,    // [4096][128]
    const float* __restrict__ base,   // [4096][128]
    float* __restrict__ xout)         // [4096][128]
{
  __shared__ float h3l[16*H3STR];
  __shared__ float zl[16*128];
  __shared__ float El[16*128];

  const int tid = threadIdx.x;
  const int b0 = blockIdx.x * 16;

  // stage h3 transposed into [batch][h] rows (pads zeroed: garbage would NaN)
  {
    const int b = tid >> 5, hs = tid & 31;
    for (int h = hs; h < H3STR; h += 32)
      h3l[b*H3STR + h] = (h < HPN) ? h3t[(size_t)h*BATCHN + b0 + b] : 0.f;
  }
  for (int i = tid; i < 16*128; i += 512) {
    int bbi = i >> 7, c = i & 127;
    zl[i] = z_t[(size_t)(b0+bbi)*DIMN + c];
    El[i] = 0.f;
  }
  __syncthreads();

  const int bq = tid >> 6;   // 0..7 : wave -> 2 batches
  const int kq = tid & 63;   // lane -> 8 consecutive k
  const float* h3A = h3l + (bq*2)  *H3STR;
  const float* h3B = h3l + (bq*2+1)*H3STR;

  for (int w = 0; w < 16; ++w) {
    const int k0 = w*512 + kq*8;
    const float* wbase = WT + (size_t)k0*HP4;
    float accA[8], accB[8];
    #pragma unroll
    for (int i=0;i<8;++i) { accA[i] = 0.f; accB[i] = 0.f; }

    #pragma unroll 2
    for (int hc = 0; hc < HP4/4; ++hc) {
      const float4 ha = *(const float4*)&h3A[hc*4];
      const float4 hb = *(const float4*)&h3B[hc*4];
      #pragma unroll
      for (int kk = 0; kk < 8; ++kk) {
        const float4 wv = *(const float4*)&wbase[kk*HP4 + hc*4];
        accA[kk] = fmaf(wv.x, ha.x, accA[kk]);
        accA[kk] = fmaf(wv.y, ha.y, accA[kk]);
        accA[kk] = fmaf(wv.z, ha.z, accA[kk]);
        accA[kk] = fmaf(wv.w, ha.w, accA[kk]);
        accB[kk] = fmaf(wv.x, hb.x, accB[kk]);
        accB[kk] = fmaf(wv.y, hb.y, accB[kk]);
        accB[kk] = fmaf(wv.z, hb.z, accB[kk]);
        accB[kk] = fmaf(wv.w, hb.w, accB[kk]);
      }
    }

    if (k0 < 8128) {   // 8-groups never straddle 8128 (multiple of 8)
      int kr[8], kc[8];
      #pragma unroll
      for (int i=0;i<8;++i) {
        int k = k0 + i;
        int r = tri_row(k);
        kr[i] = r;
        kc[i] = k - (r*(r-1))/2;
      }
      const int bA = bq*2, bB = bA+1;
      {
        float run = 0.f; int cur = kr[0];
        #pragma unroll
        for (int i=0;i<8;++i) {
          float p = accA[i] * zl[bA*128 + kc[i]];
          if (kr[i] == cur) run += p;
          else { atomicAdd(&El[bA*128 + cur], run); cur = kr[i]; run = p; }
        }
        atomicAdd(&El[bA*128 + cur], run);
      }
      {
        float run = 0.f; int cur = kr[0];
        #pragma unroll
        for (int i=0;i<8;++i) {
          float p = accB[i] * zl[bB*128 + kc[i]];
          if (kr[i] == cur) run += p;
          else { atomicAdd(&El[bB*128 + cur], run); cur = kr[i]; run = p; }
        }
        atomicAdd(&El[bB*128 + cur], run);
      }
    }
  }
  __syncthreads();

  {
    const int i = tid*4;   // 512 thr x 4 floats = 2048 = 16*128
    const int bbi = i >> 7;
    const float4 bs = *(const float4*)&base[(size_t)(b0+bbi)*DIMN + (i & 127)];
    const float4 ev = *(const float4*)&El[i];
    float4 o; o.x = bs.x+ev.x; o.y = bs.y+ev.y; o.z = bs.z+ev.z; o.w = bs.w+ev.w;
    *(float4*)&xout[(size_t)(b0+bbi)*DIMN + (i & 127)] = o;
  }
}

// ---- epilogue kernels
__global__ __launch_bounds__(256) void huber_kernel(const float* __restrict__ o,
    const float* __restrict__ y, float* __restrict__ dst)
{
  __shared__ float r[4];
  int idx = blockIdx.x*256 + threadIdx.x;
  float hub = 0.f;
  for (int i = idx; i < BATCHN*DIMN; i += 256*256) {
    float e = o[i] - y[i], ae = fabsf(e);
    hub += (ae <= 0.5f) ? 0.5f*e*e : fmaf(0.5f, ae, -0.125f);
  }
  #pragma unroll
  for (int off=32; off>0; off>>=1) hub += __shfl_down(hub, off);
  if ((threadIdx.x & 63) == 0) r[threadIdx.x>>6] = hub;
  __syncthreads();
  if (threadIdx.x == 0) atomicAdd(dst, r[0]+r[1]+r[2]+r[3]);
}

__global__ void finalize_kernel(const float* __restrict__ hub_sum,
    const float* __restrict__ ent_sum, float* __restrict__ out)
{
  int i = threadIdx.x;
  if (i < NSTEPSN) {
    const float c1 = (1.0f/NSTEPSN)/(float)(BATCHN*DIMN);
    const float c2 = (1.0f/NSTEPSN)*0.0001f/(float)BATCHN;
    float s = 0.f;
    for (int j = NSTEPSN-1; j >= i; --j) s += hub_sum[j]*c1 - ent_sum[j]*c2;
    out[i] = s;
  }
}

extern "C" void kernel_launch(void* const* d_in, const int* in_sizes, int n_in,
                              void* d_out, int out_size, void* d_ws, size_t ws_size,
                              hipStream_t stream) {
  const float* init_state = (const float*)d_in[0];
  const float* yhat = (const float*)d_in[1];
  const float* z    = (const float*)d_in[2];
  Weights wt;
  wt.W1d = (const float*)d_in[5];  wt.b1d = (const float*)d_in[6];
  wt.W2d = (const float*)d_in[7];  wt.b2d = (const float*)d_in[8];
  wt.W3d = (const float*)d_in[9];  wt.b3d = (const float*)d_in[10];
  wt.Wod = (const float*)d_in[11]; wt.bod = (const float*)d_in[12];
  wt.W1f = (const float*)d_in[13]; wt.b1f = (const float*)d_in[14];
  wt.W2f = (const float*)d_in[15]; wt.b2f = (const float*)d_in[16];
  wt.W3f = (const float*)d_in[17]; wt.b3f = (const float*)d_in[18];
  const float* diff_Wo = (const float*)d_in[19];
  const float* diff_bo = (const float*)d_in[20];

  float* ws = (float*)d_ws;
  float* WT     = ws;                        // 8192*104
  float* Wdiag  = WT + (size_t)KPAD*HP4;     // 12800
  float* bdiag  = Wdiag + HIDN*128;          // 128
  float* h3t    = bdiag + 128;               // 101*4096
  float* base   = h3t + (size_t)HPN*BATCHN;  // 4096*128
  float* bufA   = base + (size_t)BATCHN*DIMN;
  float* bufB   = bufA + (size_t)BATCHN*DIMN;
  float* Wpack  = bufB + (size_t)BATCHN*DIMN; // 6*128*128
  float* hub_sum = Wpack + 6*128*128;         // 64
  float* ent_sum = hub_sum + 64;              // 64
  wt.Wdiag = Wdiag; wt.bdiag = bdiag;

  hipMemsetAsync(hub_sum, 0, 128*sizeof(float), stream);
  init_wt<<<KPAD, 128, 0, stream>>>(diff_Wo, diff_bo, WT);
  init_misc<<<(HIDN*128 + 128 + BATCHN + 255)/256, 256, 0, stream>>>(
      diff_Wo, diff_bo, Wdiag, bdiag, h3t);
  init_pack<<<(6*128*128)/256, 256, 0, stream>>>(wt, Wpack);

  const float* xin = init_state;
  for (int t = 0; t < NSTEPSN; ++t) {
    float* xout = (t & 1) ? bufB : bufA;
    const float* zt = z + (size_t)t*BATCHN*DIMN;
    const float* yp = t ? (yhat + (size_t)(t-1)*BATCHN*DIMN) : nullptr;
    mlp_kernel<<<256, 256, 0, stream>>>(xin, yp, zt, wt, Wpack, base, h3t,
                                        hub_sum, ent_sum, t);
    heavy_kernel<<<256, 512, 0, stream>>>(h3t, WT, zt, base, xout);
    xin = xout;
  }
  huber_kernel<<<256, 256, 0, stream>>>(xin, yhat + (size_t)(NSTEPSN-1)*BATCHN*DIMN,
                                        hub_sum + (NSTEPSN-1));
  finalize_kernel<<<1, 64, 0, stream>>>(hub_sum, ent_sum, (float*)d_out);
}

// Round 4
// 10916.824 us; speedup vs baseline: 8.4215x; 8.4215x over previous
//
#include <hip/hip_runtime.h>
#include <math.h>

#define BATCHN 4096
#define DIMN 128
#define HIDN 100
#define NSTEPSN 50
#define KPAD 8192   // strict-lower 8128 padded to 8192
#define HPN 101     // 100 hidden + 1 bias row
#define HP4 104     // HPN padded to multiple of 4 (pad rows/cols = 0)
#define KSLICES 4   // k-split factor for TLP

struct Weights {
  const float *W1d,*b1d,*W2d,*b2d,*W3d,*b3d,*Wod,*bod;
  const float *W1f,*b1f,*W2f,*b2f,*W3f,*b3f;
  const float *Wdiag,*bdiag;
};

// ---- k -> (row) for strict-lower packed index: k = r*(r-1)/2 + c, c<r
__device__ inline int tri_row(int k) {
  float rf = (1.0f + sqrtf(1.0f + 8.0f*(float)k)) * 0.5f;
  int r = (int)rf;
  if (k < (r*(r-1))/2) --r;
  else if (k >= (r*(r+1))/2) ++r;
  return r;
}
// fill_triangular: cat = [v[:,128:], v[:,::-1]]; element (r,c) of the 128x128
// reshape comes from v[kk+128] if kk<8128 else v[16383-kk], kk = r*128+c.
__device__ inline int cat_vidx(int r, int c) {
  int kk = r*128 + c;
  return (kk < 8128) ? (kk + 128) : (16383 - kk);
}

// ---- init: h-major permuted strict-lower output weights.
// Wperm[h][k], h=100 is bias row, h=101..103 zero pad, k>=8128 zero pad.
__global__ __launch_bounds__(256) void init_wperm(const float* __restrict__ Wo,
    const float* __restrict__ bo, float* __restrict__ Wperm)
{
  int idx = blockIdx.x*256 + threadIdx.x;
  if (idx >= HP4*KPAD) return;
  int h = idx >> 13, k = idx & (KPAD-1);
  float val = 0.f;
  if (k < 8128 && h <= HIDN) {
    int r = tri_row(k);
    int c = k - (r*(r-1))/2;
    int vidx = cat_vidx(r, c);
    val = (h < HIDN) ? Wo[h*8256 + vidx] : bo[vidx];
  }
  Wperm[idx] = val;
}

// ---- init: diagonal weight slice + diag bias
__global__ __launch_bounds__(256) void init_misc(const float* __restrict__ Wo,
    const float* __restrict__ bo, float* __restrict__ Wdiag,
    float* __restrict__ bdiag)
{
  int idx = blockIdx.x*256 + threadIdx.x;
  if (idx < HIDN*128) {
    int h = idx >> 7, r = idx & 127;
    Wdiag[idx] = Wo[h*8256 + cat_vidx(r, r)];
  } else if (idx < HIDN*128 + 128) {
    int r = idx - HIDN*128;
    bdiag[r] = bo[cat_vidx(r, r)];
  }
}

// ---- init: zero-padded Kx128 packs of the six narrow (.,100) matrices
__global__ __launch_bounds__(256) void init_pack(Weights wt, float* __restrict__ Wpack)
{
  int idx = blockIdx.x*256 + threadIdx.x;
  if (idx >= 6*128*128) return;
  int m = idx >> 14, rem = idx & 16383, c = rem >> 7, j = rem & 127;
  const float* src; int K;
  switch (m) {
    case 0: src = wt.W1d; K = 128; break;
    case 1: src = wt.W2d; K = 100; break;
    case 2: src = wt.W3d; K = 100; break;
    case 3: src = wt.W1f; K = 128; break;
    case 4: src = wt.W2f; K = 100; break;
    default: src = wt.W3f; K = 100; break;
  }
  Wpack[idx] = (j < HIDN && c < K) ? src[c*HIDN + j] : 0.f;
}

// ---- K1: both MLPs, drift out, vdiag, base->xbase, huber(t-1), entropy.
// xin is reconstructed as xbase_prev + sum(E4 slices) when E4prev != null.
__global__ __launch_bounds__(256) void mlp_kernel(
    const float* __restrict__ xin, const float* __restrict__ E4prev,
    const float* __restrict__ yhat_prev,
    const float* __restrict__ z_t, Weights wt, const float* __restrict__ Wpack,
    float* __restrict__ xbase_out, float* __restrict__ h3b,
    float* __restrict__ hub_sum, float* __restrict__ ent_sum, int t)
{
  __shared__ float Wl[128*128];
  __shared__ float xinl[16*132];
  __shared__ float hA[16*132];
  __shared__ float hB[16*132];
  __shared__ float redw[4];
  __shared__ float redh[16];

  const int tid = threadIdx.x;
  const int b0 = blockIdx.x * 16;
  const int bb = tid >> 4;
  const int jt = tid & 15;
  const int j0 = jt * 8;

  // stage x tile (16x128), summing E4 partials, + fused Huber(t-1)
  {
    const int f = tid * 8;
    const int lb = f >> 7, c = f & 127;
    const float* xp = xin + (size_t)(b0+lb)*DIMN + c;
    float4 x0 = *(const float4*)xp;
    float4 x1 = *(const float4*)(xp+4);
    if (E4prev) {
      #pragma unroll
      for (int s = 0; s < KSLICES; ++s) {
        const float* ep = E4prev + ((size_t)s*BATCHN + b0+lb)*DIMN + c;
        const float4 e0 = *(const float4*)ep;
        const float4 e1 = *(const float4*)(ep+4);
        x0.x+=e0.x; x0.y+=e0.y; x0.z+=e0.z; x0.w+=e0.w;
        x1.x+=e1.x; x1.y+=e1.y; x1.z+=e1.z; x1.w+=e1.w;
      }
    }
    *(float4*)&xinl[lb*132+c]   = x0;
    *(float4*)&xinl[lb*132+c+4] = x1;
    if (yhat_prev) {
      const float* yp = yhat_prev + (size_t)(b0+lb)*DIMN + c;
      float4 y0 = *(const float4*)yp;
      float4 y1 = *(const float4*)(yp+4);
      float xv[8] = {x0.x,x0.y,x0.z,x0.w,x1.x,x1.y,x1.z,x1.w};
      float yv[8] = {y0.x,y0.y,y0.z,y0.w,y1.x,y1.y,y1.z,y1.w};
      float hub = 0.f;
      #pragma unroll
      for (int i=0;i<8;++i) {
        float e = xv[i]-yv[i], ae = fabsf(e);
        hub += (ae <= 0.5f) ? 0.5f*e*e : fmaf(0.5f, ae, -0.125f);
      }
      #pragma unroll
      for (int off=32; off>0; off>>=1) hub += __shfl_down(hub, off);
      if ((tid & 63) == 0) redw[tid>>6] = hub;
    }
  }
  __syncthreads();
  if (yhat_prev && tid == 0)
    atomicAdd(&hub_sum[t-1], redw[0]+redw[1]+redw[2]+redw[3]);

  float acc[8];

  auto stage = [&](const float* __restrict__ Wg, int K) {
    __syncthreads();
    for (int i = tid*4; i < K*128; i += 1024)
      *(float4*)&Wl[i] = *(const float4*)&Wg[i];
    __syncthreads();
  };
  auto compute = [&](const float* inl, int K) {
    #pragma unroll
    for (int i=0;i<8;++i) acc[i] = 0.f;
    const float* inrow = inl + bb*132;
    #pragma unroll 4
    for (int c = 0; c < K; ++c) {
      const float xv = inrow[c];
      const float4 w0 = *(const float4*)&Wl[c*128 + j0];
      const float4 w1 = *(const float4*)&Wl[c*128 + j0 + 4];
      acc[0] = fmaf(xv, w0.x, acc[0]);
      acc[1] = fmaf(xv, w0.y, acc[1]);
      acc[2] = fmaf(xv, w0.z, acc[2]);
      acc[3] = fmaf(xv, w0.w, acc[3]);
      acc[4] = fmaf(xv, w1.x, acc[4]);
      acc[5] = fmaf(xv, w1.y, acc[5]);
      acc[6] = fmaf(xv, w1.z, acc[6]);
      acc[7] = fmaf(xv, w1.w, acc[7]);
    }
  };

  const float* P_W1d = Wpack;
  const float* P_W2d = Wpack + 16384;
  const float* P_W3d = Wpack + 32768;
  const float* P_W1f = Wpack + 49152;
  const float* P_W2f = Wpack + 65536;
  const float* P_W3f = Wpack + 81920;

  float h1reg[8], driftreg[8];

  // ---------- drift net ----------
  stage(P_W1d, 128); compute(xinl, 128);
  #pragma unroll
  for (int i=0;i<8;++i) {
    int j = j0+i;
    float v = (j < HIDN) ? tanhf(acc[i] + wt.b1d[j]) : 0.f;
    h1reg[i] = v; hA[bb*132+j] = v;
  }
  stage(P_W2d, 100); compute(hA, 100);
  #pragma unroll
  for (int i=0;i<8;++i) {
    int j = j0+i;
    float v = (j < HIDN) ? (tanhf(acc[i] + wt.b2d[j]) + h1reg[i]) : 0.f;
    hB[bb*132+j] = v;
  }
  stage(P_W3d, 100); compute(hB, 100);
  #pragma unroll
  for (int i=0;i<8;++i) {
    int j = j0+i;
    float v = (j < HIDN) ? fmaxf(acc[i] + wt.b3d[j], 0.f) : 0.f;
    hA[bb*132+j] = v;
  }
  stage(wt.Wod, 100); compute(hA, 100);
  #pragma unroll
  for (int i=0;i<8;++i) driftreg[i] = acc[i] + wt.bod[j0+i];

  // ---------- diff net ----------
  stage(P_W1f, 128); compute(xinl, 128);
  #pragma unroll
  for (int i=0;i<8;++i) {
    int j = j0+i;
    float v = (j < HIDN) ? tanhf(acc[i] + wt.b1f[j]) : 0.f;
    h1reg[i] = v; hB[bb*132+j] = v;
  }
  stage(P_W2f, 100); compute(hB, 100);
  #pragma unroll
  for (int i=0;i<8;++i) {
    int j = j0+i;
    float v = (j < HIDN) ? (tanhf(acc[i] + wt.b2f[j]) + h1reg[i]) : 0.f;
    hA[bb*132+j] = v;
  }
  stage(P_W3f, 100); compute(hA, 100);
  {
    float sv[8];
    #pragma unroll
    for (int i=0;i<8;++i) {
      int j = j0+i;
      float v = (j < HIDN) ? fmaxf(acc[i] + wt.b3f[j], 0.f) : 0.f;
      hB[bb*132+j] = v;
      sv[i] = (j < HIDN) ? v : ((j == HIDN) ? 1.f : 0.f);  // bias row + zero pads
    }
    if (j0 < HP4) {  // jt <= 12 covers [0,104)
      float* hp = h3b + (size_t)(b0+bb)*HP4 + j0;
      *(float4*)hp     = make_float4(sv[0],sv[1],sv[2],sv[3]);
      *(float4*)(hp+4) = make_float4(sv[4],sv[5],sv[6],sv[7]);
    }
  }
  stage(wt.Wdiag, 100); compute(hB, 100);

  // ---------- epilogue: vdiag, entropy, xbase ----------
  {
    float entacc = 0.f;
    const float* zp = z_t + (size_t)(b0+bb)*DIMN + j0;
    const float* xrow = xinl + bb*132 + j0;
    float o8[8];
    #pragma unroll
    for (int i=0;i<8;++i) {
      int j = j0+i;
      float vd = acc[i] + wt.bdiag[j];
      entacc += vd;                       // log(det) = sum of raw diag (log∘exp)
      o8[i] = xrow[i] + driftreg[i] + expf(vd) * zp[i];
    }
    float* bp = xbase_out + (size_t)(b0+bb)*DIMN + j0;
    *(float4*)bp     = make_float4(o8[0],o8[1],o8[2],o8[3]);
    *(float4*)(bp+4) = make_float4(o8[4],o8[5],o8[6],o8[7]);
    #pragma unroll
    for (int off=8; off>0; off>>=1) entacc += __shfl_down(entacc, off, 16);
    if (jt == 0) redh[bb] = entacc;
    __syncthreads();
    if (tid == 0) {
      float s = 0.f;
      #pragma unroll
      for (int i=0;i<16;++i) s += redh[i];
      atomicAdd(&ent_sum[t], s);
    }
  }
}

// ---- K2: partial V=h3aug@Wperm consumed into E-slice (coalesced h-major reads,
// k-split across blockIdx.y for 4 waves/SIMD TLP without extra Wperm traffic)
__global__ __launch_bounds__(256, 4) void heavy_kernel(
    const float* __restrict__ h3b,    // [4096][104]
    const float* __restrict__ Wperm,  // [104][8192] h-major
    const float* __restrict__ z_t,    // [4096][128]
    float* __restrict__ E4)           // [KSLICES][4096][128]
{
  __shared__ float h3l[16*112];
  __shared__ float zl[16*128];
  __shared__ float El[16*128];

  const int tid = threadIdx.x;
  const int b0 = blockIdx.x * 16;
  const int slice = blockIdx.y;

  // stage h3 rows [b][0..103] (float4-coalesced)
  {
    const int b = tid >> 4, hs = tid & 15;
    float4* dst = (float4*)(h3l + b*112);
    const float4* src = (const float4*)(h3b + (size_t)(b0+b)*HP4);
    for (int c = hs; c < HP4/4; c += 16) dst[c] = src[c];
  }
  for (int i = tid; i < 16*128; i += 256) {
    int bbi = i >> 7, c = i & 127;
    zl[i] = z_t[(size_t)(b0+bbi)*DIMN + c];
    El[i] = 0.f;
  }
  __syncthreads();

  const int bq = tid >> 6;   // 0..3 : wave -> 4 batches
  const int kq = tid & 63;   // lane -> 8 consecutive k
  const float* h3p = h3l + bq*4*112;

  for (int w = slice*4; w < slice*4 + 4; ++w) {
    const int k0 = w*512 + kq*8;
    float acc[4][8];
    #pragma unroll
    for (int bi=0;bi<4;++bi)
      #pragma unroll
      for (int i=0;i<8;++i) acc[bi][i] = 0.f;

    const float* wp = Wperm + k0;
    #pragma unroll 2
    for (int hc = 0; hc < HP4/4; ++hc) {
      float hcol[4][4];
      *(float4*)&hcol[0][0] = *(const float4*)&h3p[hc*4];
      *(float4*)&hcol[1][0] = *(const float4*)&h3p[112 + hc*4];
      *(float4*)&hcol[2][0] = *(const float4*)&h3p[224 + hc*4];
      *(float4*)&hcol[3][0] = *(const float4*)&h3p[336 + hc*4];
      #pragma unroll
      for (int hh = 0; hh < 4; ++hh) {
        const size_t hrow = (size_t)(hc*4+hh)*KPAD;
        const float4 wa = *(const float4*)&wp[hrow];
        const float4 wb = *(const float4*)&wp[hrow + 4];
        const float w8[8] = {wa.x,wa.y,wa.z,wa.w, wb.x,wb.y,wb.z,wb.w};
        #pragma unroll
        for (int bi=0; bi<4; ++bi) {
          const float hv = hcol[bi][hh];
          #pragma unroll
          for (int i=0;i<8;++i) acc[bi][i] = fmaf(hv, w8[i], acc[bi][i]);
        }
      }
    }

    if (k0 < 8128) {   // 8-groups never straddle 8128 (both multiples of 8)
      int kr[8], kc[8];
      #pragma unroll
      for (int i=0;i<8;++i) {
        int k = k0 + i;
        int r = tri_row(k);
        kr[i] = r;
        kc[i] = k - (r*(r-1))/2;
      }
      #pragma unroll
      for (int bi=0;bi<4;++bi) {
        const int b = bq*4 + bi;
        float run = 0.f; int cur = kr[0];
        #pragma unroll
        for (int i=0;i<8;++i) {
          float p = acc[bi][i] * zl[b*128 + kc[i]];
          if (kr[i] == cur) run += p;
          else { atomicAdd(&El[b*128 + cur], run); cur = kr[i]; run = p; }
        }
        atomicAdd(&El[b*128 + cur], run);
      }
    }
  }
  __syncthreads();

  // write this block's partial E to its slice (coalesced, deterministic)
  {
    float* eout = E4 + ((size_t)slice*BATCHN + b0)*DIMN;
    const int i = tid*8;
    *(float4*)&eout[i]   = *(const float4*)&El[i];
    *(float4*)&eout[i+4] = *(const float4*)&El[i+4];
  }
}

// ---- final-step huber: x = xbase + sum(E4 slices)
__global__ __launch_bounds__(256) void huber_kernel(const float* __restrict__ xb,
    const float* __restrict__ E4, const float* __restrict__ y,
    float* __restrict__ dst)
{
  __shared__ float r[4];
  int idx = blockIdx.x*256 + threadIdx.x;
  float hub = 0.f;
  for (int i4 = idx; i4 < BATCHN*DIMN/4; i4 += 256*256) {
    float4 x = ((const float4*)xb)[i4];
    #pragma unroll
    for (int s=0;s<KSLICES;++s) {
      const float4 e = ((const float4*)E4)[(size_t)s*(BATCHN*DIMN/4) + i4];
      x.x+=e.x; x.y+=e.y; x.z+=e.z; x.w+=e.w;
    }
    const float4 yv = ((const float4*)y)[i4];
    float ev[4] = {x.x-yv.x, x.y-yv.y, x.z-yv.z, x.w-yv.w};
    #pragma unroll
    for (int i=0;i<4;++i) {
      float ae = fabsf(ev[i]);
      hub += (ae <= 0.5f) ? 0.5f*ev[i]*ev[i] : fmaf(0.5f, ae, -0.125f);
    }
  }
  #pragma unroll
  for (int off=32; off>0; off>>=1) hub += __shfl_down(hub, off);
  if ((threadIdx.x & 63) == 0) r[threadIdx.x>>6] = hub;
  __syncthreads();
  if (threadIdx.x == 0) atomicAdd(dst, r[0]+r[1]+r[2]+r[3]);
}

__global__ void finalize_kernel(const float* __restrict__ hub_sum,
    const float* __restrict__ ent_sum, float* __restrict__ out)
{
  int i = threadIdx.x;
  if (i < NSTEPSN) {
    const float c1 = (1.0f/NSTEPSN)/(float)(BATCHN*DIMN);
    const float c2 = (1.0f/NSTEPSN)*0.0001f/(float)BATCHN;
    float s = 0.f;
    for (int j = NSTEPSN-1; j >= i; --j) s += hub_sum[j]*c1 - ent_sum[j]*c2;
    out[i] = s;
  }
}

extern "C" void kernel_launch(void* const* d_in, const int* in_sizes, int n_in,
                              void* d_out, int out_size, void* d_ws, size_t ws_size,
                              hipStream_t stream) {
  const float* init_state = (const float*)d_in[0];
  const float* yhat = (const float*)d_in[1];
  const float* z    = (const float*)d_in[2];
  Weights wt;
  wt.W1d = (const float*)d_in[5];  wt.b1d = (const float*)d_in[6];
  wt.W2d = (const float*)d_in[7];  wt.b2d = (const float*)d_in[8];
  wt.W3d = (const float*)d_in[9];  wt.b3d = (const float*)d_in[10];
  wt.Wod = (const float*)d_in[11]; wt.bod = (const float*)d_in[12];
  wt.W1f = (const float*)d_in[13]; wt.b1f = (const float*)d_in[14];
  wt.W2f = (const float*)d_in[15]; wt.b2f = (const float*)d_in[16];
  wt.W3f = (const float*)d_in[17]; wt.b3f = (const float*)d_in[18];
  const float* diff_Wo = (const float*)d_in[19];
  const float* diff_bo = (const float*)d_in[20];

  float* ws = (float*)d_ws;
  float* Wperm  = ws;                        // 104*8192 = 851968
  float* Wdiag  = Wperm + (size_t)HP4*KPAD;  // 12800
  float* bdiag  = Wdiag + HIDN*128;          // 128
  float* h3b    = bdiag + 128;               // 4096*104 = 425984
  float* xbA    = h3b + (size_t)BATCHN*HP4;  // 524288
  float* xbB    = xbA + (size_t)BATCHN*DIMN; // 524288
  float* E4     = xbB + (size_t)BATCHN*DIMN; // 4*524288 = 2097152
  float* Wpack  = E4 + (size_t)KSLICES*BATCHN*DIMN; // 98304
  float* hub_sum = Wpack + 6*128*128;        // 64
  float* ent_sum = hub_sum + 64;             // 64

  wt.Wdiag = Wdiag; wt.bdiag = bdiag;

  hipMemsetAsync(hub_sum, 0, 128*sizeof(float), stream);
  init_wperm<<<(HP4*KPAD)/256, 256, 0, stream>>>(diff_Wo, diff_bo, Wperm);
  init_misc<<<(HIDN*128 + 128 + 255)/256, 256, 0, stream>>>(
      diff_Wo, diff_bo, Wdiag, bdiag);
  init_pack<<<(6*128*128)/256, 256, 0, stream>>>(wt, Wpack);

  const float* xin = init_state;
  const float* e4in = nullptr;
  for (int t = 0; t < NSTEPSN; ++t) {
    float* xbout = (t & 1) ? xbB : xbA;
    const float* zt = z + (size_t)t*BATCHN*DIMN;
    const float* yp = t ? (yhat + (size_t)(t-1)*BATCHN*DIMN) : nullptr;
    mlp_kernel<<<256, 256, 0, stream>>>(xin, e4in, yp, zt, wt, Wpack,
                                        xbout, h3b, hub_sum, ent_sum, t);
    heavy_kernel<<<dim3(256, KSLICES), 256, 0, stream>>>(h3b, Wperm, zt, E4);
    xin = xbout; e4in = E4;
  }
  huber_kernel<<<256, 256, 0, stream>>>(xin, E4,
      yhat + (size_t)(NSTEPSN-1)*BATCHN*DIMN, hub_sum + (NSTEPSN-1));
  finalize_kernel<<<1, 64, 0, stream>>>(hub_sum, ent_sum, (float*)d_out);
}